// Round 10
// baseline (15657.594 us; speedup 1.0000x reference)
//
#include <hip/hip_runtime.h>
#include <hip/hip_bf16.h>
#include <math.h>

#define T_LEN 128
#define BATCH 64
#define IND   512
#define HDIM  256
#define NS    8
#define H4    1024
#define NTHR  512
#define RPC   8        // rows per cluster
#define CSTRIDE 67584  // floats per cluster in ws
#define WQK_BASE (1024 + 8 * CSTRIDE)   // per-cg Wq/Wk slice table (64 x 2080 floats)

typedef unsigned long long ull;
typedef unsigned int uint;
typedef unsigned short ushort;
typedef _Float16 f16x2 __attribute__((ext_vector_type(2)));
typedef _Float16 half8 __attribute__((ext_vector_type(8)));
typedef float f32x4 __attribute__((ext_vector_type(4)));

// ---- LLC-coherent accessors (bypass per-XCD L2): agent-scope relaxed atomics ----
__device__ __forceinline__ float gload(const float* p) {
  return __hip_atomic_load(p, __ATOMIC_RELAXED, __HIP_MEMORY_SCOPE_AGENT);
}
__device__ __forceinline__ float2 gload2(const float* p) {
  ull v = __hip_atomic_load((const ull*)p, __ATOMIC_RELAXED, __HIP_MEMORY_SCOPE_AGENT);
  return __builtin_bit_cast(float2, v);
}
__device__ __forceinline__ void gstore(float* p, float v) {
  __hip_atomic_store(p, v, __ATOMIC_RELAXED, __HIP_MEMORY_SCOPE_AGENT);
}
__device__ __forceinline__ void gstore2(float* p, float a, float b) {
  float2 t = make_float2(a, b);
  __hip_atomic_store((ull*)p, __builtin_bit_cast(ull, t), __ATOMIC_RELAXED, __HIP_MEMORY_SCOPE_AGENT);
}
__device__ __forceinline__ void gstoreu2(uint* p, uint a, uint b) {
  uint2 t = make_uint2(a, b);
  __hip_atomic_store((ull*)p, __builtin_bit_cast(ull, t), __ATOMIC_RELAXED, __HIP_MEMORY_SCOPE_AGENT);
}
__device__ __forceinline__ ull gloadU(const uint* p) {
  return __hip_atomic_load((const ull*)p, __ATOMIC_RELAXED, __HIP_MEMORY_SCOPE_AGENT);
}
__device__ __forceinline__ uint2 gloadu2(const uint* p) {
  ull v = __hip_atomic_load((const ull*)p, __ATOMIC_RELAXED, __HIP_MEMORY_SCOPE_AGENT);
  return __builtin_bit_cast(uint2, v);
}

// ---- f16 pack/unpack ----
__device__ __forceinline__ uint pack2(float a, float b) {
  f16x2 v; v.x = (_Float16)a; v.y = (_Float16)b;
  return __builtin_bit_cast(uint, v);
}
__device__ __forceinline__ float2 unpack2(uint u) {
  f16x2 v = __builtin_bit_cast(f16x2, u);
  return make_float2((float)v.x, (float)v.y);
}
__device__ __forceinline__ half8 mk8(ull lo, ull hi) {
  struct U { ull a, b; } u{lo, hi};
  return __builtin_bit_cast(half8, u);
}
__device__ __forceinline__ half8 bc8(uint4 v) {
  return __builtin_bit_cast(half8, v);
}

// fast tanh via hw exp
__device__ __forceinline__ float ftanh(float x) {
  float xc = fminf(fmaxf(x, -9.f), 9.f);
  float t = __expf(2.f * xc);
  return (t - 1.f) * __builtin_amdgcn_rcpf(t + 1.f);
}

extern "C" __global__ void init_ctrl(int* ctrl) {
  int t = blockIdx.x * blockDim.x + threadIdx.x;
  if (t < 1024) ctrl[t] = 0;
}

// ---------------- Xp = tanh(LN(X @ W_proj + b)) ----------------
extern "C" __global__ __launch_bounds__(256) void xp_kernel(
    const float* __restrict__ X, const float* __restrict__ Wp, const float* __restrict__ bp,
    const float* __restrict__ lns, const float* __restrict__ lnb, float* __restrict__ out_xp)
{
  __shared__ float Xs[8 * IND];
  __shared__ float Ys[8 * HDIM];
  const int tid = threadIdx.x;
  const size_t base = (size_t)blockIdx.x * 8;
  const float* Xb = X + base * IND;
  for (int e = tid; e < 8 * IND / 4; e += 256) ((float4*)Xs)[e] = ((const float4*)Xb)[e];
  __syncthreads();
  float acc[8];
#pragma unroll
  for (int r = 0; r < 8; ++r) acc[r] = 0.f;
  for (int k = 0; k < IND; ++k) {
    float wv = Wp[k * HDIM + tid];
#pragma unroll
    for (int r = 0; r < 8; ++r) acc[r] += Xs[r * IND + k] * wv;
  }
  float bpv = bp[tid];
#pragma unroll
  for (int r = 0; r < 8; ++r) Ys[r * HDIM + tid] = acc[r] + bpv;
  __syncthreads();
  int w = tid >> 6, lane = tid & 63;
  for (int rr = 0; rr < 2; ++rr) {
    int r = w * 2 + rr;
    float v[4]; float s1 = 0.f, s2 = 0.f;
#pragma unroll
    for (int e = 0; e < 4; ++e) { v[e] = Ys[r * HDIM + lane + 64 * e]; s1 += v[e]; s2 += v[e] * v[e]; }
#pragma unroll
    for (int off = 32; off > 0; off >>= 1) { s1 += __shfl_xor(s1, off, 64); s2 += __shfl_xor(s2, off, 64); }
    float m = s1 / 256.f;
    float iv = rsqrtf(s2 / 256.f - m * m + 1e-5f);
#pragma unroll
    for (int e = 0; e < 4; ++e) {
      int hd = lane + 64 * e;
      out_xp[(base + r) * HDIM + hd] = tanhf((v[e] - m) * iv * lns[hd] + lnb[hd]);
    }
  }
}

// ws float layout: [0..1023] int flags (cluster cl: ints [cl*64, cl*64+64)), 8 clusters;
// data base = 1024; per cluster cl (8 clusters of 8 rows), stride 67584:
//   QPRE +0 (2048), KPRE +2048 (16384), MB0 +18432 (16384), MB1 +34816 (16384),
//   Z1c +51200 (f16x2: 8*512 uints), Z2c +59392 (f16x2: 8*512 uints)
// WQK_BASE: 64 x 2080 floats (Wq own-cols [4x260] at +0, Wk at +1040)

// ---------------- main recurrent kernel: 8 clusters x 64 blocks, 2 blocks/CU ----------------
extern "C" __global__ __launch_bounds__(NTHR, 4) void omr_main(
    const float* __restrict__ Xp,
    const float* __restrict__ Wq, const float* __restrict__ bq,
    const float* __restrict__ lnqs, const float* __restrict__ lnqb,
    const float* __restrict__ Wk, const float* __restrict__ bk,
    const float* __restrict__ lnks, const float* __restrict__ lnkb,
    const float* __restrict__ Wbeta, const float* __restrict__ bbeta,
    const float* __restrict__ W1, const float* __restrict__ b1,
    const float* __restrict__ W2, const float* __restrict__ b2,
    const float* __restrict__ lns, const float* __restrict__ lnb,
    float* __restrict__ mem_out, float* __restrict__ probs_out, float* __restrict__ ws)
{
  const int tid = threadIdx.x;
  const int clid = blockIdx.x >> 6;  // cluster 0..7 (8 rows each)
  const int cg = blockIdx.x & 63;    // column group within cluster
  const int ZC0 = cg * 16;           // z1/z2 cols owned
  const int QC0 = cg * 4;            // q/k/h cols owned
  const int row0 = clid * RPC;
  const int w = tid >> 6, lane = tid & 63;

  // LDS ~70 KB -> 2 blocks/CU
  __shared__ uint W1b[16 * 260];     // f16x2 W1 col slice [col][kpair]
  __shared__ uint W2b[16 * 516];     // f16x2 W2 col slice [col][kpair]
  __shared__ uint hloc[RPC * 132];   // f16x2 rows
  __shared__ uint Ast[RPC * 132];
  __shared__ uint Az[RPC * 132];     // q-LN staging (f16x2)
  __shared__ float redS[8 * 260];    // split-K partials (16x16, rows 0-7 valid)
  __shared__ float cpS[64], rcpS[64], betaS[64];
  __shared__ float b1s[16], b2s[16], bqS[4], bkS[4], bbetaS[1];

  float* base_ = ws + 1024 + (size_t)clid * CSTRIDE;
  float* QPRE  = base_;
  float* KPRE  = base_ + 2048;
  float* MB0   = base_ + 18432;
  float* MB1   = base_ + 34816;
  uint*  Z1u   = (uint*)(base_ + 51200);
  uint*  Z2u   = (uint*)(base_ + 59392);
  int*   flags = (int*)ws + clid * 64;
  float* WQW   = ws + WQK_BASE + (size_t)cg * 2080;   // Wq slice [4x260]
  float* WKW   = WQW + 1040;                          // Wk slice [4x260]

  // ---- resident weights / params (f16 pairs along K) ----
  for (int e = tid; e < 16 * 256; e += NTHR) {
    int kp = e >> 4, c = e & 15;
    W1b[c * 260 + kp] = pack2(W1[(size_t)(2 * kp) * H4 + ZC0 + c],
                              W1[(size_t)(2 * kp + 1) * H4 + ZC0 + c]);
  }
  for (int e = tid; e < 16 * 512; e += NTHR) {
    int kp = e >> 4, c = e & 15;
    W2b[c * 516 + kp] = pack2(W2[(size_t)(2 * kp) * H4 + ZC0 + c],
                              W2[(size_t)(2 * kp + 1) * H4 + ZC0 + c]);
  }
  // Wq/Wk own-col slices to ws (all 8 same-cg blocks write identical values; each
  // block writes the FULL slice so self-visibility via own stores is guaranteed)
  for (int e = tid; e < 2048; e += NTHR) {
    int s = e >> 10, c = (e >> 8) & 3, k = e & 255;
    gstore((s ? WKW : WQW) + c * 260 + k, (s ? Wk : Wq)[k * HDIM + QC0 + c]);
  }
  if (tid < 16) { b1s[tid] = b1[ZC0 + tid]; b2s[tid] = b2[ZC0 + tid]; }
  if (tid < 4)  { bqS[tid] = bq[QC0 + tid]; bkS[tid] = bk[QC0 + tid]; }
  if (tid == 0) bbetaS[0] = bbeta[0];

  // ---- barrier primitives (s_sleep yields SIMD to co-resident block) ----
  auto waitF = [&](int p) {
    if (tid < 64) {
      while (__hip_atomic_load(flags + tid, __ATOMIC_RELAXED, __HIP_MEMORY_SCOPE_AGENT) < p)
        __builtin_amdgcn_s_sleep(1);
    }
    __syncthreads();
  };
  auto sig = [&](int p) {
    asm volatile("s_waitcnt vmcnt(0)" ::: "memory");
    __syncthreads();
    if (tid == 0) __hip_atomic_store(flags + cg, p, __ATOMIC_RELAXED, __HIP_MEMORY_SCOPE_AGENT);
  };

  // ==== MFMA GEMM helpers (16x16x32 f16; rows 0-7 valid, 8-15 zero) ====
  auto z1Mfma = [&](const uint* A, int kwBaseP, f32x4& acc) {
    const int row16 = lane & 15, kg = lane >> 4;
    uint4 av = make_uint4(0u, 0u, 0u, 0u);
    if (row16 < 8) av = *(const uint4*)(A + row16 * 132 + w * 16 + kg * 4);
    uint4 bv = *(const uint4*)&W1b[row16 * 260 + kwBaseP + w * 16 + kg * 4];
    acc = __builtin_amdgcn_mfma_f32_16x16x32_f16(bc8(av), bc8(bv), acc, 0, 0, 0);
  };
  // reduce split-K partials over 8 waves; pack f16x2, store rows 0-7 to dst (512-uint rows)
  auto redFinishMF = [&](f32x4 acc, uint* dst, const float* bias, bool doRelu) {
    __syncthreads();                    // protect prior redS readers
    const int col = lane & 15, rbase = (lane >> 4) * 4;
#pragma unroll
    for (int q = 0; q < 4; ++q)
      redS[w * 260 + (rbase + q) * 16 + col] = acc[q];
    __syncthreads();
    if (tid < 32) {
      int r = tid >> 2, c0 = (tid & 3) * 4;
      float v[4] = {0.f, 0.f, 0.f, 0.f};
#pragma unroll
      for (int w2 = 0; w2 < 8; ++w2) {
#pragma unroll
        for (int q = 0; q < 4; ++q) v[q] += redS[w2 * 260 + r * 16 + c0 + q];
      }
#pragma unroll
      for (int q = 0; q < 4; ++q) {
        v[q] += bias[c0 + q];
        if (doRelu) v[q] = fmaxf(v[q], 0.f);
      }
      gstoreu2(dst + r * 512 + (ZC0 + c0) / 2, pack2(v[0], v[1]), pack2(v[2], v[3]));
    }
  };

  // ---- 4-col projections (wave w = row w; 16 lanes per col) ----
  auto projQ = [&](const float* A /*plain global row*/, float* dst) {
    int col = lane >> 4, kp = lane & 15;
    const float* Wc = WQW + col * 260 + kp * 16;
    const float* Ak = A + kp * 16;
    float d = 0.f;
#pragma unroll
    for (int k4 = 0; k4 < 4; ++k4) {
      float4 a = *(const float4*)(Ak + 4 * k4);
      float4 wv = *(const float4*)(Wc + 4 * k4);
      d += a.x * wv.x + a.y * wv.y + a.z * wv.z + a.w * wv.w;
    }
    d += __shfl_xor(d, 1, 64); d += __shfl_xor(d, 2, 64);
    d += __shfl_xor(d, 4, 64); d += __shfl_xor(d, 8, 64);
    if (kp == 0) gstore(dst + col, d + bqS[col]);
  };
  auto projK_G = [&](const float* A /*LLC row (gload)*/, float* dst) {
    int col = lane >> 4, kp = lane & 15;
    const float* Wc = WKW + col * 260 + kp * 16;
    const float* Ak = A + kp * 16;
    float v0[16];
#pragma unroll
    for (int k2 = 0; k2 < 8; ++k2) {
      float2 a = gload2(Ak + 2 * k2);
      v0[2 * k2] = a.x; v0[2 * k2 + 1] = a.y;
    }
    float d = 0.f;
#pragma unroll
    for (int e = 0; e < 16; ++e) d += v0[e] * Wc[e];
    d += __shfl_xor(d, 1, 64); d += __shfl_xor(d, 2, 64);
    d += __shfl_xor(d, 4, 64); d += __shfl_xor(d, 8, 64);
    if (kp == 0) gstore(dst + col, d + bkS[col]);
  };
  auto projK_L = [&](const uint* A /*LDS f16 row*/, float* dst) {
    int col = lane >> 4, kp = lane & 15;
    const float* Wc = WKW + col * 260 + kp * 16;
    float d = 0.f;
#pragma unroll
    for (int q = 0; q < 2; ++q) {
      uint4 a0 = *(const uint4*)&A[kp * 8 + q * 4];
      const float* wq = Wc + q * 8;
      float2 p0 = unpack2(a0.x), p1 = unpack2(a0.y), p2 = unpack2(a0.z), p3 = unpack2(a0.w);
      d += p0.x * wq[0] + p0.y * wq[1] + p1.x * wq[2] + p1.y * wq[3]
         + p2.x * wq[4] + p2.y * wq[5] + p3.x * wq[6] + p3.y * wq[7];
    }
    d += __shfl_xor(d, 1, 64); d += __shfl_xor(d, 2, 64);
    d += __shfl_xor(d, 4, 64); d += __shfl_xor(d, 8, 64);
    if (kp == 0) gstore(dst + col, d + bkS[col]);
  };

  // ================= t=0 init =================
  {
    if (tid < 256) {
      int e = cg * 256 + tid;          // 16384 floats over 64 blocks
      gstore(MB0 + e, 0.f);
      int r = e >> 11, s = (e >> 8) & 7, hd = e & 255;
      gstore(mem_out + ((size_t)(row0 + r) * NS + s) * HDIM + hd,
             Xp[(size_t)(row0 + r) * HDIM + hd]);
    }
    if (cg == 0 && tid < 64) gstore(probs_out + row0 * NS + tid, 0.f);
    {
      int r = tid >> 6, c4 = lane * 4;   // prestage hloc = Xp[t=1] (pack f16)
      const float* src = &Xp[((size_t)BATCH + row0 + r) * HDIM + c4];
      float4 a = *(const float4*)src;
      *(uint2*)&hloc[r * 132 + lane * 2] = make_uint2(pack2(a.x, a.y), pack2(a.z, a.w));
    }
  }
  // drain WQW/WKW stores before local plain reads
  asm volatile("s_waitcnt vmcnt(0)" ::: "memory");
  __syncthreads();
  // S1a for t=1: q from Xp[1], k from Xp[0] broadcast to all slots
  {
    projQ(Xp + ((size_t)BATCH + row0 + w) * HDIM, QPRE + w * HDIM + QC0);
    int col = lane >> 4, kp = lane & 15;
    const float* Wc = WKW + col * 260 + kp * 16;
    const float* Ak = Xp + (size_t)(row0 + w) * HDIM + kp * 16;
    float d = 0.f;
#pragma unroll
    for (int k4 = 0; k4 < 4; ++k4) {
      float4 a = *(const float4*)(Ak + 4 * k4);
      float4 wv = *(const float4*)(Wc + 4 * k4);
      d += a.x * wv.x + a.y * wv.y + a.z * wv.z + a.w * wv.w;
    }
    d += __shfl_xor(d, 1, 64); d += __shfl_xor(d, 2, 64);
    d += __shfl_xor(d, 4, 64); d += __shfl_xor(d, 8, 64);
    if (kp == 0) {
      float vk = d + bkS[col];
#pragma unroll
      for (int s = 0; s < NS; ++s) gstore(KPRE + (w * 8 + s) * HDIM + QC0 + col, vk);
    }
  }
  int ph = 1;
  sig(ph);
  waitF(ph);

  // ================= time loop =================
  for (int t = 1; t < T_LEN; ++t) {
    const bool lastT = (t == T_LEN - 1);
    float* MbOld = ((t - 1) & 1) ? MB1 : MB0;
    float* MbNew = (t & 1) ? MB1 : MB0;
    const float* memPrev = mem_out + (size_t)(t - 1) * BATCH * NS * HDIM;
    float* memCur = mem_out + (size_t)t * BATCH * NS * HDIM;
    const float* probsPrev = probs_out + (size_t)(t - 1) * BATCH * NS;
    float* probsCur = probs_out + (size_t)t * BATCH * NS;

    // ---------- P1 ----------
    // (1) q-LN pre-wait (QPRE(t) visible via waits of t-1) -> Az packed f16
    {
      const int hd0 = lane * 4;
      float2 v0 = gload2(QPRE + w * HDIM + hd0), v1 = gload2(QPRE + w * HDIM + hd0 + 2);
      float q[4] = {v0.x, v0.y, v1.x, v1.y};
      float s1 = q[0] + q[1] + q[2] + q[3];
      float s2 = q[0] * q[0] + q[1] * q[1] + q[2] * q[2] + q[3] * q[3];
#pragma unroll
      for (int m = 1; m < 64; m <<= 1) { s1 += __shfl_xor(s1, m, 64); s2 += __shfl_xor(s2, m, 64); }
      float mean = s1 * (1.f / 256.f);
      float inv = rsqrtf(s2 * (1.f / 256.f) - mean * mean + 1e-5f);
      float4 qs = *(const float4*)&lnqs[hd0];
      float4 qb = *(const float4*)&lnqb[hd0];
      *(uint2*)&Az[w * 132 + lane * 2] = make_uint2(
          pack2((q[0] - mean) * inv * qs.x + qb.x, (q[1] - mean) * inv * qs.y + qb.y),
          pack2((q[2] - mean) * inv * qs.z + qb.z, (q[3] - mean) * inv * qs.w + qb.w));
    }
    // wait for all blocks' B(7) of t-1 (KPRE fresh) — hidden under q-LN above
    waitF(ph);
    {
      // (2) k-LN + beta: 64 krows x 8 threads (32 floats each)
      const int kr = tid >> 3, u8 = tid & 7, rr = kr >> 3;
      const float* kp = KPRE + kr * HDIM + u8 * 32;
      float kv[32]; float s1 = 0.f, s2 = 0.f;
#pragma unroll
      for (int e = 0; e < 16; ++e) {
        float2 v = gload2(kp + 2 * e);
        kv[2 * e] = v.x; kv[2 * e + 1] = v.y;
        s1 += v.x + v.y; s2 += v.x * v.x + v.y * v.y;
      }
      s1 += __shfl_xor(s1, 1, 64); s1 += __shfl_xor(s1, 2, 64); s1 += __shfl_xor(s1, 4, 64);
      s2 += __shfl_xor(s2, 1, 64); s2 += __shfl_xor(s2, 2, 64); s2 += __shfl_xor(s2, 4, 64);
      float mean = s1 * (1.f / 256.f);
      float inv = rsqrtf(s2 * (1.f / 256.f) - mean * mean + 1e-5f);
      float dot = 0.f;
#pragma unroll
      for (int e = 0; e < 32; e += 2) {
        int hd = u8 * 32 + e;
        float2 q2 = unpack2(Az[rr * 132 + hd / 2]);
        float kl0 = (kv[e] - mean) * inv * lnks[hd] + lnkb[hd];
        float kl1 = (kv[e + 1] - mean) * inv * lnks[hd + 1] + lnkb[hd + 1];
        dot += fmaxf(q2.x + kl0, 0.f) * Wbeta[hd];
        dot += fmaxf(q2.y + kl1, 0.f) * Wbeta[hd + 1];
      }
      dot += __shfl_xor(dot, 1, 64); dot += __shfl_xor(dot, 2, 64); dot += __shfl_xor(dot, 4, 64);
      if (u8 == 0) betaS[kr] = (dot + bbetaS[0]) * 0.0625f;
    }
    __syncthreads();
    // (3) softmax + mask + p/cp/rcp (8 threads)
    if (tid < 8) {
      int r = tid, b = row0 + r;
      float pp[8], pcp[8], run = 0.f;
#pragma unroll
      for (int s = 0; s < 8; s += 2) {
        float2 v = gload2(probsPrev + b * NS + s);
        pp[s] = v.x; pp[s + 1] = v.y;
      }
#pragma unroll
      for (int s = 0; s < 8; ++s) { run += pp[s]; pcp[s] = run; }
      float bmax = betaS[r * 8];
#pragma unroll
      for (int s = 1; s < 8; ++s) bmax = fmaxf(bmax, betaS[r * 8 + s]);
      float xm[8], ssum = 0.f;
#pragma unroll
      for (int s = 0; s < 8; ++s) {
        float mi = (s < 7) ? ((pcp[s + 1] < 1e-5f) ? 0.f : pcp[s + 1]) : 1.f;
        xm[s] = __expf(betaS[r * 8 + s] - bmax) * mi;
        ssum += fabsf(xm[s]);
      }
      float denom = fmaxf(ssum, 1e-12f);
      float run2 = 0.f, pn[8];
#pragma unroll
      for (int s = 0; s < 8; ++s) {
        pn[s] = xm[s] / denom; run2 += pn[s];
        cpS[r * 8 + s] = run2;
      }
      if (cg == r) {
#pragma unroll
        for (int s = 0; s < 8; s += 2) gstore2(probsCur + b * NS + s, pn[s], pn[s + 1]);
      }
      float run3 = 0.f;
#pragma unroll
      for (int s = 7; s >= 0; --s) { run3 += pn[s]; rcpS[r * 8 + s] = run3; }
    }
    __syncthreads();
    // (4) M-state owner update (own 4 cols, 8 rows x 8 slots)
    if (tid < 256) {
      int r = tid >> 5, s = (tid >> 2) & 7, c = tid & 3;
      int idx = (r * NS + s) * HDIM + QC0 + c;
      float rc = rcpS[r * 8 + s];
      float mo = gload(MbOld + idx);
      float cm = gload(memPrev + ((size_t)(row0 + r) * NS + s) * HDIM + QC0 + c);
      gstore(MbNew + idx, mo * (1.f - rc) + cm * rc);
    }
    // (5) stage Ast = blend(MbOld, memPrev) slot0, pack f16 (hloc prestaged)
    {
      const int r = tid >> 6, c4 = lane * 4;
      float rc0 = rcpS[r * 8];
      const float* mo = MbOld + (r * NS) * HDIM + c4;
      const float* cm = memPrev + ((size_t)(row0 + r) * NS) * HDIM + c4;
      float2 m0 = gload2(mo), m1 = gload2(mo + 2);
      float2 c0 = gload2(cm), c1 = gload2(cm + 2);
      *(uint2*)&Ast[r * 132 + lane * 2] = make_uint2(
          pack2(m0.x * (1.f - rc0) + c0.x * rc0, m0.y * (1.f - rc0) + c0.y * rc0),
          pack2(m1.x * (1.f - rc0) + c1.x * rc0, m1.y * (1.f - rc0) + c1.y * rc0));
    }
    __syncthreads();
    {
      // Z1(0) via MFMA: Mn-half (Ast, k[256..512)) + h-half (hloc, k[0..256))
      f32x4 acc = {0.f, 0.f, 0.f, 0.f};
      z1Mfma(Ast, 128, acc);
      z1Mfma(hloc, 0, acc);
      redFinishMF(acc, Z1u, b1s, true);
    }
    ++ph; sig(ph);

    // ---------- cells ----------
    for (int ci = 0; ci < NS; ++ci) {
      const int phRdy = ph;
      // ---- Z2(ci): MFMA, A-frags direct from ws ----
      {
        waitF(phRdy);
        const int row16 = lane & 15, kg = lane >> 4;
        const int kb = w * 16 + kg * 4;
        ull a0 = 0, a1 = 0, b0 = 0, b1v = 0, c0 = 0, c1 = 0, d0 = 0, d1 = 0;
        if (row16 < 8) {
          const uint* zrow = Z1u + row16 * 512;
          a0 = gloadU(zrow + kb);       a1 = gloadU(zrow + kb + 2);
          b0 = gloadU(zrow + 128 + kb); b1v = gloadU(zrow + 128 + kb + 2);
          c0 = gloadU(zrow + 256 + kb); c1 = gloadU(zrow + 256 + kb + 2);
          d0 = gloadU(zrow + 384 + kb); d1 = gloadU(zrow + 384 + kb + 2);
        }
        f32x4 acc = {0.f, 0.f, 0.f, 0.f};
        uint4 w0 = *(const uint4*)&W2b[row16 * 516 + 0 * 128 + kb];
        uint4 w1v = *(const uint4*)&W2b[row16 * 516 + 1 * 128 + kb];
        uint4 w2v = *(const uint4*)&W2b[row16 * 516 + 2 * 128 + kb];
        uint4 w3v = *(const uint4*)&W2b[row16 * 516 + 3 * 128 + kb];
        acc = __builtin_amdgcn_mfma_f32_16x16x32_f16(mk8(a0, a1), bc8(w0), acc, 0, 0, 0);
        acc = __builtin_amdgcn_mfma_f32_16x16x32_f16(mk8(b0, b1v), bc8(w1v), acc, 0, 0, 0);
        acc = __builtin_amdgcn_mfma_f32_16x16x32_f16(mk8(c0, c1), bc8(w2v), acc, 0, 0, 0);
        acc = __builtin_amdgcn_mfma_f32_16x16x32_f16(mk8(d0, d1), bc8(w3v), acc, 0, 0, 0);
        redFinishMF(acc, Z2u, b2s, false);
      }
      ++ph; sig(ph);   // signal A(ci)
      const int phA = ph;

      // ======== window A: overlap with peers' Z2 completion ========
      float4 hv;
      {
        uint2 u0 = *(const uint2*)&Ast[w * 132 + lane * 2];
        float2 a = unpack2(u0.x), b = unpack2(u0.y);
        hv = make_float4(a.x, a.y, b.x, b.y);
      }
      __syncthreads();
      if (ci < 7) {
        // restage Ast = MbNew slot ci+1 (fully blended in P1), pack f16
        const int r = tid >> 6, c4 = lane * 4;
        const float* src = MbNew + (r * NS + ci + 1) * HDIM + c4;
        float2 a0 = gload2(src), a1 = gload2(src + 2);
        *(uint2*)&Ast[r * 132 + lane * 2] =
            make_uint2(pack2(a0.x, a0.y), pack2(a1.x, a1.y));
      } else if (!lastT) {
        // KPRE(s=6): memCur slot 6 visible (waited sigB(6) in Z2(7))
        projK_G(memCur + ((size_t)(row0 + w) * NS + 6) * HDIM,
                KPRE + (w * 8 + 6) * HDIM + QC0);
      }
      __syncthreads();
      f32x4 bacc = {0.f, 0.f, 0.f, 0.f};
      if (ci < 7) z1Mfma(Ast, 128, bacc);   // Mn-half of Z1(ci+1)
      waitF(phA);

      // ---- H(ci): wave w = row w, 4 h-dims per lane ----
      {
        const int hd0 = lane * 4;
        const uint* z2r = Z2u + w * 512;
        uint2 cu = gloadu2(z2r + 384 + lane * 2);
        uint2 ga = gloadu2(z2r + 6 * lane), gb = gloadu2(z2r + 6 * lane + 2),
              gc = gloadu2(z2r + 6 * lane + 4);
        float cc[4];
        {
          float2 x = unpack2(cu.x), y = unpack2(cu.y);
          cc[0] = x.x; cc[1] = x.y; cc[2] = y.x; cc[3] = y.y;
        }
        float g[12];
        {
          float2 t0 = unpack2(ga.x), t1 = unpack2(ga.y), t2 = unpack2(gb.x),
                 t3 = unpack2(gb.y), t4 = unpack2(gc.x), t5 = unpack2(gc.y);
          g[0] = t0.x; g[1] = t0.y; g[2] = t1.x; g[3] = t1.y;
          g[4] = t2.x; g[5] = t2.y; g[6] = t3.x; g[7] = t3.y;
          g[8] = t4.x; g[9] = t4.y; g[10] = t5.x; g[11] = t5.y;
        }
        float s1 = cc[0] + cc[1] + cc[2] + cc[3];
        float s2 = cc[0] * cc[0] + cc[1] * cc[1] + cc[2] * cc[2] + cc[3] * cc[3];
#pragma unroll
        for (int m = 1; m < 64; m <<= 1) { s1 += __shfl_xor(s1, m, 64); s2 += __shfl_xor(s2, m, 64); }
        float mean = s1 * (1.f / 256.f);
        float inv = rsqrtf(s2 * (1.f / 256.f) - mean * mean + 1e-5f);
        float viv[4];
        {
          uint2 vu = *(const uint2*)&hloc[w * 132 + lane * 2];
          float2 x = unpack2(vu.x), y = unpack2(vu.y);
          viv[0] = x.x; viv[1] = x.y; viv[2] = y.x; viv[3] = y.y;
        }
        float4 xp4 = *(const float4*)&Xp[((size_t)t * BATCH + row0 + w) * HDIM + hd0];
        float4 ls4 = *(const float4*)&lns[hd0];
        float4 lb4 = *(const float4*)&lnb[hd0];
        float xpv[4] = {xp4.x, xp4.y, xp4.z, xp4.w};
        float hivv[4] = {hv.x, hv.y, hv.z, hv.w};
        float lsv[4] = {ls4.x, ls4.y, ls4.z, ls4.w};
        float lbv[4] = {lb4.x, lb4.y, lb4.z, lb4.w};
        float cp = cpS[w * 8 + ci];
        float hn[4];
#pragma unroll
        for (int j = 0; j < 4; ++j) {
          float z0 = g[3 * j], z1v = g[3 * j + 1], z2g = g[3 * j + 2];
          float gm = fmaxf(z0, fmaxf(z1v, z2g));
          float e0 = __expf(z0 - gm), e1 = __expf(z1v - gm), e2 = __expf(z2g - gm);
          float act = ftanh((cc[j] - mean) * inv * lsv[j] + lbv[j]);
          float hc = (e0 * viv[j] + e1 * hivv[j] + e2 * act) * __builtin_amdgcn_rcpf(e0 + e1 + e2);
          hn[j] = xpv[j] * (1.f - cp) + hc * cp;
        }
        *(uint2*)&hloc[w * 132 + lane * 2] =
            make_uint2(pack2(hn[0], hn[1]), pack2(hn[2], hn[3]));
        if (lane == cg) {   // lane*4 == QC0: owner writes 4 cols
          float* mp = memCur + ((size_t)(row0 + w) * NS + ci) * HDIM + QC0;
          gstore2(mp, hn[0], hn[1]);
          gstore2(mp + 2, hn[2], hn[3]);
        }
      }
      __syncthreads();
      if (ci < 7) {
        z1Mfma(hloc, 0, bacc);   // h-half of Z1(ci+1)
        redFinishMF(bacc, Z1u, b1s, true);
      } else if (!lastT) {
        // KPRE(s=7) from new h (LDS f16) — pre-sigB
        projK_L(&hloc[w * 132], KPRE + (w * 8 + 7) * HDIM + QC0);
      }
      ++ph; sig(ph);   // signal B(ci)

      // ======== window B: S1a(t+1) pieces (drained by NEXT signal) ========
      if (!lastT) {
        if (ci == 0) {
          projQ(Xp + ((size_t)(t + 1) * BATCH + row0 + w) * HDIM, QPRE + w * HDIM + QC0);
        } else if (ci <= 6) {
          const int s = ci - 1;   // memCur slot s visible (waited sigB(s) in Z2(ci))
          projK_G(memCur + ((size_t)(row0 + w) * NS + s) * HDIM,
                  KPRE + (w * 8 + s) * HDIM + QC0);
        } else {
          // prestage hloc = Xp[t+1], pack f16
          const int r = tid >> 6, c4 = lane * 4;
          const float* src = &Xp[((size_t)(t + 1) * BATCH + row0 + r) * HDIM + c4];
          float4 a = *(const float4*)src;
          *(uint2*)&hloc[r * 132 + lane * 2] =
              make_uint2(pack2(a.x, a.y), pack2(a.z, a.w));
        }
      }
    }
    // no end-of-loop wait — next P1's q-LN runs pre-wait; waitF(ph) after q-LN
  }
}

extern "C" void kernel_launch(void* const* d_in, const int* in_sizes, int n_in,
                              void* d_out, int out_size, void* d_ws, size_t ws_size,
                              hipStream_t stream) {
  (void)in_sizes; (void)n_in; (void)out_size; (void)ws_size;
  const float* X     = (const float*)d_in[0];
  const float* Wp    = (const float*)d_in[3];
  const float* bp    = (const float*)d_in[4];
  const float* lns   = (const float*)d_in[5];
  const float* lnb   = (const float*)d_in[6];
  const float* Wq    = (const float*)d_in[7];
  const float* bq    = (const float*)d_in[8];
  const float* lnqs  = (const float*)d_in[9];
  const float* lnqb  = (const float*)d_in[10];
  const float* Wk    = (const float*)d_in[11];
  const float* bk    = (const float*)d_in[12];
  const float* lnks  = (const float*)d_in[13];
  const float* lnkb  = (const float*)d_in[14];
  const float* Wbeta = (const float*)d_in[15];
  const float* bbeta = (const float*)d_in[16];
  const float* W1    = (const float*)d_in[17];
  const float* b1    = (const float*)d_in[18];
  const float* W2    = (const float*)d_in[19];
  const float* b2    = (const float*)d_in[20];

  float* out       = (float*)d_out;
  float* out_xp    = out;
  float* out_mem   = out + (size_t)T_LEN * BATCH * HDIM;
  float* out_probs = out_mem + (size_t)T_LEN * BATCH * NS * HDIM;
  float* ws        = (float*)d_ws;

  hipLaunchKernelGGL(init_ctrl, dim3(4), dim3(256), 0, stream, (int*)d_ws);
  hipLaunchKernelGGL(xp_kernel, dim3(1024), dim3(256), 0, stream, X, Wp, bp, lns, lnb, out_xp);
  hipLaunchKernelGGL(omr_main, dim3(512), dim3(NTHR), 0, stream,
                     out_xp, Wq, bq, lnqs, lnqb, Wk, bk, lnks, lnkb, Wbeta, bbeta,
                     W1, b1, W2, b2, lns, lnb, out_mem, out_probs, ws);
}